// Round 3
// baseline (790.677 us; speedup 1.0000x reference)
//
#include <hip/hip_runtime.h>
#include <math.h>

#define B_ 2
#define S_ 1024
#define D_ 512
#define N_ 4096
#define H_ 8
#define DH_ 64
#define NCAND 288   // 9 neighbor cells * 32 entries
#define TOPK 32
#define NTOK (B_*S_)   // 2048

#define TJ 16        // attention j-tile per LDS stage
#define NROWS 16384  // B*H*S

// ---------- block-wide reductions (256 threads = 4 waves) ----------
__device__ __forceinline__ float blk_sum(float v, float* sc) {
    #pragma unroll
    for (int o = 32; o; o >>= 1) v += __shfl_xor(v, o);
    __syncthreads();
    if ((threadIdx.x & 63) == 0) sc[threadIdx.x >> 6] = v;
    __syncthreads();
    return sc[0] + sc[1] + sc[2] + sc[3];
}
__device__ __forceinline__ float blk_max(float v, float* sc) {
    #pragma unroll
    for (int o = 32; o; o >>= 1) v = fmaxf(v, __shfl_xor(v, o));
    __syncthreads();
    if ((threadIdx.x & 63) == 0) sc[threadIdx.x >> 6] = v;
    __syncthreads();
    return fmaxf(fmaxf(sc[0], sc[1]), fmaxf(sc[2], sc[3]));
}

// ---------- threshold gate (wave-cooperative ballot top-k) ----------
// writes final scaled gate values into w[]; eg[] is scratch.
__device__ __forceinline__ void gate_compute(
    const float* __restrict__ act, const float* __restrict__ msk, float tau,
    float* eg, float* w, float* sc)
{
    const int t = threadIdx.x, wid = t >> 6, lane = t & 63;
    for (int c = t; c < NCAND; c += 256) {
        float s    = (msk[c] != 0.f) ? act[c] : -1e9f;
        float raw  = s - tau;
        float gate = (raw > 0.f) ? raw : 1e-8f * __expf(raw);
        eg[c] = __expf(gate) - 1.f;
    }
    __syncthreads();
    // each lane preloads a strided slice of eg (eg >= 0 always, so -1 = never greater)
    float ej[5];
    #pragma unroll
    for (int k = 0; k < 5; k++) {
        int j = lane + 64 * k;
        ej[k] = (j < NCAND) ? eg[j] : -1.f;
    }
    // wave counts strictly-greater for its 72 elements via ballot+popcount
    for (int e = wid * 72; e < wid * 72 + 72; e++) {
        float ev = eg[e];                       // LDS broadcast
        int cgt = 0;
        #pragma unroll
        for (int k = 0; k < 5; k++)
            cgt += __popcll(__ballot(ej[k] > ev));
        if (lane == 0) w[e] = (cgt < TOPK) ? ev : 0.f;   // keep iff #greater < K
    }
    __syncthreads();
    float v0 = w[t];
    float v1 = (t < NCAND - 256) ? w[t + 256] : 0.f;
    float gs = blk_sum(v0 + v1, sc) + 1e-8f;
    float mx = blk_max(fmaxf(v0, v1), sc);
    float scale = tanhf(mx) / gs;
    w[t] = v0 * scale;
    if (t < NCAND - 256) w[t + 256] = v1 * scale;
    __syncthreads();
}

// ---------- token sort by spatial cell (1 block, 1024 threads) ----------
__global__ __launch_bounds__(1024) void sort_tokens_kernel(
    const float* __restrict__ qk_pos, const float* __restrict__ v_pos,
    const float* __restrict__ pos_min, const float* __restrict__ pos_range,
    int* __restrict__ order_qk, int* __restrict__ order_v)
{
    __shared__ int hist[256], offs[256], tmp[256];
    const int t = threadIdx.x;
    const float pm0 = pos_min[0], pm1 = pos_min[1];
    const float pr0 = pos_range[0], pr1 = pos_range[1];
    for (int pass = 0; pass < 2; pass++) {
        const float* pos = pass ? v_pos : qk_pos;
        int* order = pass ? order_v : order_qk;
        if (t < 256) hist[t] = 0;
        __syncthreads();
        int cell[2];
        #pragma unroll
        for (int k = 0; k < 2; k++) {
            int tok = t + k * 1024;
            float p0 = pos[tok * 2], p1 = pos[tok * 2 + 1];
            int cx = min(max((int)((p0 - pm0) / pr0 * 16.f), 0), 15);
            int cy = min(max((int)((p1 - pm1) / pr1 * 16.f), 0), 15);
            cell[k] = cx * 16 + cy;
            atomicAdd(&hist[cell[k]], 1);
        }
        __syncthreads();
        if (t < 256) tmp[t] = hist[t];
        __syncthreads();
        for (int d = 1; d < 256; d <<= 1) {
            int v = 0;
            if (t < 256 && t >= d) v = tmp[t - d];
            __syncthreads();
            if (t < 256) tmp[t] += v;
            __syncthreads();
        }
        if (t < 256) offs[t] = tmp[t] - hist[t];
        __syncthreads();
        #pragma unroll
        for (int k = 0; k < 2; k++) {
            int tok = t + k * 1024;
            int p = atomicAdd(&offs[cell[k]], 1);
            order[p] = tok;
        }
        __syncthreads();
    }
}

// ---------- QK kernel: one block per token (sorted order, XCD-swizzled) ----------
__global__ __launch_bounds__(256) void qk_kernel(
    const int* __restrict__ order,
    const float* __restrict__ x, const float* __restrict__ qk_pos,
    const float* __restrict__ tauQ, const float* __restrict__ tauK,
    const float* __restrict__ neurons, const float* __restrict__ npos,
    const int* __restrict__ cmap,
    const float* __restrict__ pos_min, const float* __restrict__ pos_range,
    float* __restrict__ Q, float* __restrict__ K, float* __restrict__ posacc)
{
    __shared__ int   idx[NCAND];
    __shared__ float msk[NCAND], act[NCAND], eg[NCAND];
    __shared__ float w1[NCAND], w2[NCAND];
    __shared__ int   lidx[NCAND];
    __shared__ float lwq[NCAND], lwk[NCAND];
    __shared__ float sc[4];
    __shared__ int   cnt;

    // XCD swizzle: 8 consecutive sorted positions land on the same XCD
    const int pos = (blockIdx.x >> 3) | ((blockIdx.x & 7) << 8);
    const int token = order[pos];
    const int s_pos = token & 1023;
    const int t = threadIdx.x, wid = t >> 6, lane = t & 63;
    const int g = lane >> 4, sub = lane & 15;

    const float qp0 = qk_pos[token * 2], qp1 = qk_pos[token * 2 + 1];
    const float pm0 = pos_min[0], pm1 = pos_min[1];
    const float pr0 = pos_range[0], pr1 = pos_range[1];
    const int cx = min(max((int)((qp0 - pm0) / pr0 * 16.f), 0), 15);
    const int cy = min(max((int)((qp1 - pm1) / pr1 * 16.f), 0), 15);
    for (int c = t; c < NCAND; c += 256) {
        int o = c >> 5, mslot = c & 31;
        int nx = min(max(cx + o / 3 - 1, 0), 15), ny = min(max(cy + o % 3 - 1, 0), 15);
        int cand = cmap[(nx * 16 + ny) * 32 + mslot];
        idx[c] = cand >= 0 ? cand : 0;
        msk[c] = cand >= 0 ? 1.f : 0.f;
    }
    __syncthreads();

    // x slice (32 dims) in registers; 16-lane group g owns candidate base+g
    float xr[32];
    {
        const float4* xp = (const float4*)(x + (size_t)token * D_ + sub * 32);
        #pragma unroll
        for (int k = 0; k < 8; k++) {
            float4 v = xp[k];
            xr[4*k] = v.x; xr[4*k+1] = v.y; xr[4*k+2] = v.z; xr[4*k+3] = v.w;
        }
    }
    for (int r = 0; r < 18; r++) {
        const int c = wid * 72 + r * 4 + g;
        const float4* rp = (const float4*)(neurons + (size_t)idx[c] * D_ + sub * 32);
        float a0 = 0.f, a1 = 0.f;
        #pragma unroll
        for (int k = 0; k < 8; k += 2) {
            float4 v = rp[k], u = rp[k+1];
            a0 += xr[4*k]*v.x + xr[4*k+1]*v.y + xr[4*k+2]*v.z + xr[4*k+3]*v.w;
            a1 += xr[4*k+4]*u.x + xr[4*k+5]*u.y + xr[4*k+6]*u.z + xr[4*k+7]*u.w;
        }
        float a = a0 + a1;
        a += __shfl_xor(a, 8); a += __shfl_xor(a, 4);
        a += __shfl_xor(a, 2); a += __shfl_xor(a, 1);
        if (sub == 0) act[c] = a;
    }
    __syncthreads();

    const float tq = tauQ[token], tk = tauK[token];
    gate_compute(act, msk, tq, eg, w1, sc);
    gate_compute(act, msk, tk, eg, w2, sc);

    // final weights + pos loss (Q gate only, per reference)
    float plq = 0.f, cm = 0.f;
    for (int c = t; c < NCAND; c += 256) {
        float m = msk[c], a = act[c], gq = w1[c];
        w1[c] = a * gq * m;
        w2[c] = a * w2[c] * m;
        int id = idx[c];
        float d0 = qp0 - npos[id * 2], d1 = qp1 - npos[id * 2 + 1];
        plq += gq * (d0 * d0 + d1 * d1) * m;
        cm  += m;
    }
    plq = blk_sum(plq, sc);
    cm  = blk_sum(cm, sc);
    if (t == 0) {
        int chunk = s_pos >> 7;
        atomicAdd(&posacc[chunk], plq);
        atomicAdd(&posacc[8 + chunk], cm);
        cnt = 0;
    }
    __syncthreads();
    for (int c = t; c < NCAND; c += 256) {
        float a = w1[c], b = w2[c];
        if (a != 0.f || b != 0.f) {
            int p = atomicAdd(&cnt, 1);
            lidx[p] = idx[c]; lwq[p] = a; lwk[p] = b;
        }
    }
    __syncthreads();
    const int n = cnt;
    float q0 = 0, q1 = 0, k0 = 0, k1 = 0;
    for (int p = 0; p < n; p++) {
        const float* row = neurons + (size_t)lidx[p] * D_;
        float aw = lwq[p], bw = lwk[p];
        float r0 = row[t], r1 = row[t + 256];
        q0 += aw * r0; q1 += aw * r1;
        k0 += bw * r0; k1 += bw * r1;
    }
    const size_t base = (size_t)token * D_;
    Q[base + t] = q0; Q[base + t + 256] = q1;
    K[base + t] = k0; K[base + t + 256] = k1;
}

// ---------- V kernel ----------
__global__ __launch_bounds__(256) void v_kernel(
    const int* __restrict__ order,
    const float* __restrict__ x, const float* __restrict__ v_pos,
    const float* __restrict__ tauV,
    const float* __restrict__ neurons, const float* __restrict__ npos,
    const int* __restrict__ cmap,
    const float* __restrict__ pos_min, const float* __restrict__ pos_range,
    float* __restrict__ V, float* __restrict__ posacc)
{
    __shared__ int   idx[NCAND];
    __shared__ float msk[NCAND], act[NCAND], eg[NCAND];
    __shared__ float w1[NCAND];
    __shared__ int   lidx[NCAND];
    __shared__ float lwv[NCAND];
    __shared__ float sc[4];
    __shared__ int   cnt;

    const int pos = (blockIdx.x >> 3) | ((blockIdx.x & 7) << 8);
    const int token = order[pos];
    const int s_pos = token & 1023;
    const int t = threadIdx.x, wid = t >> 6, lane = t & 63;
    const int g = lane >> 4, sub = lane & 15;

    const float vp0 = v_pos[token * 2], vp1 = v_pos[token * 2 + 1];
    const float pm0 = pos_min[0], pm1 = pos_min[1];
    const float pr0 = pos_range[0], pr1 = pos_range[1];
    const int cx = min(max((int)((vp0 - pm0) / pr0 * 16.f), 0), 15);
    const int cy = min(max((int)((vp1 - pm1) / pr1 * 16.f), 0), 15);
    for (int c = t; c < NCAND; c += 256) {
        int o = c >> 5, mslot = c & 31;
        int nx = min(max(cx + o / 3 - 1, 0), 15), ny = min(max(cy + o % 3 - 1, 0), 15);
        int cand = cmap[(nx * 16 + ny) * 32 + mslot];
        idx[c] = cand >= 0 ? cand : 0;
        msk[c] = cand >= 0 ? 1.f : 0.f;
    }
    __syncthreads();

    float xr[32];
    {
        const float4* xp = (const float4*)(x + (size_t)token * D_ + sub * 32);
        #pragma unroll
        for (int k = 0; k < 8; k++) {
            float4 v = xp[k];
            xr[4*k] = v.x; xr[4*k+1] = v.y; xr[4*k+2] = v.z; xr[4*k+3] = v.w;
        }
    }
    for (int r = 0; r < 18; r++) {
        const int c = wid * 72 + r * 4 + g;
        const float4* rp = (const float4*)(neurons + (size_t)idx[c] * D_ + sub * 32);
        float a0 = 0.f, a1 = 0.f;
        #pragma unroll
        for (int k = 0; k < 8; k += 2) {
            float4 v = rp[k], u = rp[k+1];
            a0 += xr[4*k]*v.x + xr[4*k+1]*v.y + xr[4*k+2]*v.z + xr[4*k+3]*v.w;
            a1 += xr[4*k+4]*u.x + xr[4*k+5]*u.y + xr[4*k+6]*u.z + xr[4*k+7]*u.w;
        }
        float a = a0 + a1;
        a += __shfl_xor(a, 8); a += __shfl_xor(a, 4);
        a += __shfl_xor(a, 2); a += __shfl_xor(a, 1);
        if (sub == 0) act[c] = a;
    }
    __syncthreads();

    gate_compute(act, msk, tauV[token], eg, w1, sc);

    float plv = 0.f, cm = 0.f;
    for (int c = t; c < NCAND; c += 256) {
        float m = msk[c], a = act[c], gv = w1[c];
        w1[c] = a * gv * m;
        int id = idx[c];
        float d0 = vp0 - npos[id * 2], d1 = vp1 - npos[id * 2 + 1];
        plv += gv * (d0 * d0 + d1 * d1) * m;
        cm  += m;
    }
    plv = blk_sum(plv, sc);
    cm  = blk_sum(cm, sc);
    if (t == 0) {
        int chunk = s_pos >> 7;
        atomicAdd(&posacc[16 + chunk], plv);
        atomicAdd(&posacc[24 + chunk], cm);
        cnt = 0;
    }
    __syncthreads();
    for (int c = t; c < NCAND; c += 256) {
        float a = w1[c];
        if (a != 0.f) {
            int p = atomicAdd(&cnt, 1);
            lidx[p] = idx[c]; lwv[p] = a;
        }
    }
    __syncthreads();
    const int n = cnt;
    float v0 = 0, v1 = 0;
    for (int p = 0; p < n; p++) {
        const float* row = neurons + (size_t)lidx[p] * D_;
        float aw = lwv[p];
        v0 += aw * row[t]; v1 += aw * row[t + 256];
    }
    const size_t base = (size_t)token * D_;
    V[base + t] = v0; V[base + t + 256] = v1;
}

// ---------- attention partials (causal-only compact grid) ----------
// grid: 16 bh * (10*jpr) blocks; per bh, rb has (rb+1)*jpr splits.
__global__ __launch_bounds__(256, 2) void attn_partial_kernel(
    const float* __restrict__ Q, const float* __restrict__ K,
    const float* __restrict__ V,
    float* __restrict__ pm, float* __restrict__ pl, float* __restrict__ po,
    int jspan, int jpr)
{
    const int per_bh = 10 * jpr;
    const int bh = blockIdx.x / per_bh;
    int id = blockIdx.x % per_bh;
    int rb = 0;
    while (id >= (rb + 1) * jpr) { id -= (rb + 1) * jpr; rb++; }
    const int sp = id;
    const int b = bh >> 3, h = bh & 7;
    const int j0 = sp * jspan;
    const int t = threadIdx.x;
    const int i = rb * 256 + t;
    const int maxi = rb * 256 + 255;

    __shared__ float Kl[TJ][68];
    __shared__ float Vl[TJ][68];

    float q[64];
    {
        const float4* q4 = (const float4*)(Q + ((size_t)(b * S_ + i)) * D_ + h * DH_);
        #pragma unroll
        for (int k = 0; k < 16; k++) {
            float4 v = q4[k];
            q[4*k] = v.x; q[4*k+1] = v.y; q[4*k+2] = v.z; q[4*k+3] = v.w;
        }
    }
    float o[64];
    #pragma unroll
    for (int d = 0; d < 64; d++) o[d] = 0.f;
    float m = -INFINITY, l = 0.f;

    const int ntiles = min(jspan / TJ, (maxi - j0) / TJ + 1);
    const int ldrow = t >> 4, ldc = t & 15;
    const float* Kbase = K + (size_t)b * S_ * D_ + h * DH_;
    const float* Vbase = V + (size_t)b * S_ * D_ + h * DH_;

    for (int tile = 0; tile < ntiles; tile++) {
        const int jb = j0 + tile * TJ;
        __syncthreads();
        {
            const size_t off = (size_t)(jb + ldrow) * D_ + ldc * 4;
            float4 kv = *(const float4*)(Kbase + off);
            Kl[ldrow][ldc*4+0] = kv.x; Kl[ldrow][ldc*4+1] = kv.y;
            Kl[ldrow][ldc*4+2] = kv.z; Kl[ldrow][ldc*4+3] = kv.w;
            float4 vv = *(const float4*)(Vbase + off);
            Vl[ldrow][ldc*4+0] = vv.x; Vl[ldrow][ldc*4+1] = vv.y;
            Vl[ldrow][ldc*4+2] = vv.z; Vl[ldrow][ldc*4+3] = vv.w;
        }
        __syncthreads();
        if (jb > i) continue;

        float s[TJ];
        #pragma unroll
        for (int jj = 0; jj < TJ; jj++) {
            float a0 = 0.f, a1 = 0.f, a2 = 0.f, a3 = 0.f;
            #pragma unroll
            for (int d = 0; d < 64; d += 4) {
                a0 += q[d]   * Kl[jj][d];
                a1 += q[d+1] * Kl[jj][d+1];
                a2 += q[d+2] * Kl[jj][d+2];
                a3 += q[d+3] * Kl[jj][d+3];
            }
            float scv = ((a0 + a1) + (a2 + a3)) * 0.125f;
            s[jj] = (jb + jj <= i) ? scv : -INFINITY;
        }
        float tm = s[0];
        #pragma unroll
        for (int jj = 1; jj < TJ; jj++) tm = fmaxf(tm, s[jj]);
        const float nm = fmaxf(m, tm);
        const float alpha = __expf(m - nm);
        float psum = 0.f;
        #pragma unroll
        for (int jj = 0; jj < TJ; jj++) { s[jj] = __expf(s[jj] - nm); psum += s[jj]; }
        l = l * alpha + psum;
        #pragma unroll
        for (int d = 0; d < 64; d++) o[d] *= alpha;
        #pragma unroll
        for (int jj = 0; jj < TJ; jj++) {
            const float pj = s[jj];
            #pragma unroll
            for (int d = 0; d < 64; d++) o[d] += pj * Vl[jj][d];
        }
        m = nm;
    }

    const int r = bh * S_ + i;
    pm[(size_t)sp * NROWS + r] = m;
    pl[(size_t)sp * NROWS + r] = l;
    float* od = po + ((size_t)sp * NROWS + r) * 64;
    #pragma unroll
    for (int k = 0; k < 16; k++) {
        float4 v;
        v.x = o[4*k]; v.y = o[4*k+1]; v.z = o[4*k+2]; v.w = o[4*k+3];
        *(float4*)(od + 4*k) = v;
    }
}

// ---------- merge split partials ----------
__global__ __launch_bounds__(256) void attn_combine_kernel(
    const float* __restrict__ pm, const float* __restrict__ pl,
    const float* __restrict__ po, float* __restrict__ AO, int jshift)
{
    const int gth = blockIdx.x * 256 + threadIdx.x;
    const int r = gth >> 6, d = gth & 63;
    const int i = r & 1023, bh = r >> 10;
    const int b = bh >> 3, h = bh & 7;
    const int ns = (i >> jshift) + 1;
    float mstar = -INFINITY;
    for (int s = 0; s < ns; s++) mstar = fmaxf(mstar, pm[(size_t)s * NROWS + r]);
    float lstar = 0.f, ostar = 0.f;
    for (int s = 0; s < ns; s++) {
        const float w = __expf(pm[(size_t)s * NROWS + r] - mstar);
        lstar += pl[(size_t)s * NROWS + r] * w;
        ostar += po[((size_t)s * NROWS + r) * 64 + d] * w;
    }
    AO[((size_t)(b * S_ + i)) * D_ + h * DH_ + d] = ostar / lstar;
}

// ---------- projection: 4 tokens per block, W reused across tokens ----------
__global__ __launch_bounds__(256) void proj_kernel(
    const float* __restrict__ A, const float* __restrict__ W,
    float* __restrict__ out)
{
    __shared__ float rows[4][D_];
    const int blk = blockIdx.x;            // 512 blocks
    const int t = threadIdx.x;
    {
        const float4* af = (const float4*)(A + (size_t)blk * 4 * D_);
        float4* rf = (float4*)&rows[0][0];
        rf[t] = af[t]; rf[t + 256] = af[t + 256];
    }
    __syncthreads();
    float acc0[4] = {0,0,0,0}, acc1[4] = {0,0,0,0};
    for (int d = 0; d < D_; d += 4) {
        float r0[4], r1[4], r2[4], r3[4];
        *(float4*)r0 = *(const float4*)&rows[0][d];
        *(float4*)r1 = *(const float4*)&rows[1][d];
        *(float4*)r2 = *(const float4*)&rows[2][d];
        *(float4*)r3 = *(const float4*)&rows[3][d];
        #pragma unroll
        for (int j = 0; j < 4; j++) {
            float w0 = W[(size_t)(d + j) * D_ + t];
            float w1 = W[(size_t)(d + j) * D_ + t + 256];
            acc0[0] += r0[j] * w0; acc1[0] += r0[j] * w1;
            acc0[1] += r1[j] * w0; acc1[1] += r1[j] * w1;
            acc0[2] += r2[j] * w0; acc1[2] += r2[j] * w1;
            acc0[3] += r3[j] * w0; acc1[3] += r3[j] * w1;
        }
    }
    #pragma unroll
    for (int k = 0; k < 4; k++) {
        const size_t base = (size_t)(blk * 4 + k) * D_;
        out[base + t] = acc0[k];
        out[base + t + 256] = acc1[k];
    }
}

// ---------- pos-loss helpers ----------
__global__ void zero_acc_kernel(float* acc) {
    if (threadIdx.x < 32) acc[threadIdx.x] = 0.f;
}
__global__ void ploss_kernel(const float* __restrict__ acc, float* __restrict__ out) {
    float ssum = 0.f;
    for (int c = 0; c < 8; c++) {
        ssum += acc[c]      / (acc[8 + c]  + 1e-8f);
        ssum += acc[16 + c] / (acc[24 + c] + 1e-8f);
    }
    out[0] = ssum * 0.125f;
}

extern "C" void kernel_launch(void* const* d_in, const int* in_sizes, int n_in,
                              void* d_out, int out_size, void* d_ws, size_t ws_size,
                              hipStream_t stream) {
    const float* x          = (const float*)d_in[0];
    const float* qk_pos     = (const float*)d_in[1];
    const float* v_pos      = (const float*)d_in[2];
    const float* tauQ       = (const float*)d_in[3];
    const float* tauK       = (const float*)d_in[4];
    const float* tauV       = (const float*)d_in[5];
    const float* qk_neurons = (const float*)d_in[6];
    const float* v_neurons  = (const float*)d_in[7];
    const float* npos_qk    = (const float*)d_in[8];
    const float* npos_v     = (const float*)d_in[9];
    const int*   cm_qk      = (const int*)d_in[10];
    const int*   cm_v       = (const int*)d_in[11];
    const float* pos_min    = (const float*)d_in[12];
    const float* pos_range  = (const float*)d_in[13];
    const float* expand_O   = (const float*)d_in[14];

    float* ws = (float*)d_ws;
    const size_t TDf = (size_t)NTOK * D_;     // 1,048,576 floats
    float* Q   = ws;
    float* K   = ws + TDf;
    float* V   = ws + 2 * TDf;
    float* AO  = ws + 3 * TDf;
    float* acc = ws + 4 * TDf;                // 64 float slots
    int*   order_qk = (int*)(ws + 4 * TDf + 64);
    int*   order_v  = order_qk + NTOK;
    const size_t head = 4 * TDf + 64 + 2 * NTOK;   // in float units

    // choose split granularity by available workspace (constant per session)
    const size_t need4 = (head + (size_t)16 * NROWS * 66) * 4;   // 86 MB
    const int jpr    = (ws_size >= need4) ? 4 : 2;               // splits per 256 rows
    const int jspan  = 256 / jpr;
    const int jshift = (jpr == 4) ? 6 : 7;
    const int NS     = 4 * jpr;

    float* pm = ws + head;
    float* pl = pm + (size_t)NS * NROWS;
    float* po = pl + (size_t)NS * NROWS;

    float* out = (float*)d_out;

    zero_acc_kernel<<<1, 64, 0, stream>>>(acc);
    sort_tokens_kernel<<<1, 1024, 0, stream>>>(qk_pos, v_pos, pos_min, pos_range,
                                               order_qk, order_v);
    qk_kernel<<<NTOK, 256, 0, stream>>>(order_qk, x, qk_pos, tauQ, tauK,
                                        qk_neurons, npos_qk, cm_qk,
                                        pos_min, pos_range, Q, K, acc);
    v_kernel<<<NTOK, 256, 0, stream>>>(order_v, x, v_pos, tauV,
                                       v_neurons, npos_v, cm_v,
                                       pos_min, pos_range, V, acc);
    attn_partial_kernel<<<16 * 10 * jpr, 256, 0, stream>>>(Q, K, V, pm, pl, po,
                                                           jspan, jpr);
    attn_combine_kernel<<<(NROWS * 64) / 256, 256, 0, stream>>>(pm, pl, po, AO, jshift);
    proj_kernel<<<NTOK / 4, 256, 0, stream>>>(AO, expand_O, out);
    ploss_kernel<<<1, 1, 0, stream>>>(acc, out + TDf);
}

// Round 4
// 588.632 us; speedup vs baseline: 1.3432x; 1.3432x over previous
//
#include <hip/hip_runtime.h>
#include <math.h>

#define B_ 2
#define S_ 1024
#define D_ 512
#define N_ 4096
#define H_ 8
#define DH_ 64
#define NCAND 288   // 9 neighbor cells * 32 entries
#define TOPK 32
#define NTOK (B_*S_)   // 2048

#define TJ 32        // attention j-tile per LDS stage
#define NROWS 16384  // B*H*S

// ---------- block-wide reductions (256 threads = 4 waves) ----------
__device__ __forceinline__ float blk_sum(float v, float* sc) {
    #pragma unroll
    for (int o = 32; o; o >>= 1) v += __shfl_xor(v, o);
    __syncthreads();
    if ((threadIdx.x & 63) == 0) sc[threadIdx.x >> 6] = v;
    __syncthreads();
    return sc[0] + sc[1] + sc[2] + sc[3];
}
__device__ __forceinline__ float blk_max(float v, float* sc) {
    #pragma unroll
    for (int o = 32; o; o >>= 1) v = fmaxf(v, __shfl_xor(v, o));
    __syncthreads();
    if ((threadIdx.x & 63) == 0) sc[threadIdx.x >> 6] = v;
    __syncthreads();
    return fmaxf(fmaxf(sc[0], sc[1]), fmaxf(sc[2], sc[3]));
}

// ---------- token sort by spatial cell (1 block, 1024 threads) ----------
__global__ __launch_bounds__(1024) void sort_tokens_kernel(
    const float* __restrict__ qk_pos, const float* __restrict__ v_pos,
    const float* __restrict__ pos_min, const float* __restrict__ pos_range,
    int* __restrict__ order_qk, int* __restrict__ order_v)
{
    __shared__ int hist[256], offs[256], tmp[256];
    const int t = threadIdx.x;
    const float pm0 = pos_min[0], pm1 = pos_min[1];
    const float pr0 = pos_range[0], pr1 = pos_range[1];
    for (int pass = 0; pass < 2; pass++) {
        const float* pos = pass ? v_pos : qk_pos;
        int* order = pass ? order_v : order_qk;
        if (t < 256) hist[t] = 0;
        __syncthreads();
        int cell[2];
        #pragma unroll
        for (int k = 0; k < 2; k++) {
            int tok = t + k * 1024;
            float p0 = pos[tok * 2], p1 = pos[tok * 2 + 1];
            int cx = min(max((int)((p0 - pm0) / pr0 * 16.f), 0), 15);
            int cy = min(max((int)((p1 - pm1) / pr1 * 16.f), 0), 15);
            cell[k] = cx * 16 + cy;
            atomicAdd(&hist[cell[k]], 1);
        }
        __syncthreads();
        if (t < 256) tmp[t] = hist[t];
        __syncthreads();
        for (int d = 1; d < 256; d <<= 1) {
            int v = 0;
            if (t < 256 && t >= d) v = tmp[t - d];
            __syncthreads();
            if (t < 256) tmp[t] += v;
            __syncthreads();
        }
        if (t < 256) offs[t] = tmp[t] - hist[t];
        __syncthreads();
        #pragma unroll
        for (int k = 0; k < 2; k++) {
            int tok = t + k * 1024;
            int p = atomicAdd(&offs[cell[k]], 1);
            order[p] = tok;
        }
        __syncthreads();
    }
}

// ---------- QK kernel: one block per token (sorted order, XCD-swizzled) ----------
// Rank-once-by-act (gate is strictly monotone in act => same top-32 support
// for any tau); exp evaluated only for the ~32 kept candidates.
__global__ __launch_bounds__(256) void qk_kernel(
    const int* __restrict__ order,
    const float* __restrict__ x, const float* __restrict__ qk_pos,
    const float* __restrict__ tauQ, const float* __restrict__ tauK,
    const float* __restrict__ neurons, const float* __restrict__ npos,
    const int* __restrict__ cmap,
    const float* __restrict__ pos_min, const float* __restrict__ pos_range,
    float* __restrict__ Q, float* __restrict__ K, float* __restrict__ posacc)
{
    __shared__ int   idx[NCAND];
    __shared__ float msk[NCAND], act[NCAND];
    __shared__ int   ci[NCAND];            // kept slot -> later neuron id
    __shared__ float cwq[NCAND], cwk[NCAND];
    __shared__ float sc[4];
    __shared__ int   cnt;

    const int pos = (blockIdx.x >> 3) | ((blockIdx.x & 7) << 8);  // XCD swizzle
    const int token = order[pos];
    const int s_pos = token & 1023;
    const int t = threadIdx.x, wid = t >> 6, lane = t & 63;

    const float qp0 = qk_pos[token * 2], qp1 = qk_pos[token * 2 + 1];
    const float pm0 = pos_min[0], pm1 = pos_min[1];
    const float pr0 = pos_range[0], pr1 = pos_range[1];
    const int cx = min(max((int)((qp0 - pm0) / pr0 * 16.f), 0), 15);
    const int cy = min(max((int)((qp1 - pm1) / pr1 * 16.f), 0), 15);
    for (int c = t; c < NCAND; c += 256) {
        int o = c >> 5, mslot = c & 31;
        int nx = min(max(cx + o / 3 - 1, 0), 15), ny = min(max(cy + o % 3 - 1, 0), 15);
        int cand = cmap[(nx * 16 + ny) * 32 + mslot];
        idx[c] = cand >= 0 ? cand : 0;
        msk[c] = cand >= 0 ? 1.f : 0.f;
    }
    if (t == 0) cnt = 0;
    __syncthreads();

    // --- dots: wave-per-candidate, fully coalesced (lane reads 8 contiguous) ---
    const float4* x4 = (const float4*)(x + (size_t)token * D_);
    const float4 xa = x4[lane * 2], xb = x4[lane * 2 + 1];
    for (int c = wid * 72; c < wid * 72 + 72; ++c) {
        const float4* r4 = (const float4*)(neurons + (size_t)idx[c] * D_);
        float4 ra = r4[lane * 2], rb = r4[lane * 2 + 1];
        float a = xa.x * ra.x + xa.y * ra.y + xa.z * ra.z + xa.w * ra.w +
                  xb.x * rb.x + xb.y * rb.y + xb.z * rb.z + xb.w * rb.w;
        #pragma unroll
        for (int o = 32; o; o >>= 1) a += __shfl_xor(a, o);
        if (lane == 0) act[c] = (msk[c] != 0.f) ? a : -1e9f;
    }
    __syncthreads();

    // --- rank by act via ballot+popcount; compact kept slots ---
    float ej[5];
    #pragma unroll
    for (int k = 0; k < 5; k++) {
        int j = lane + 64 * k;
        ej[k] = (j < NCAND) ? act[j] : -1e30f;
    }
    for (int e = wid * 72; e < wid * 72 + 72; e++) {
        float ev = act[e];                  // LDS broadcast
        int cgt = 0;
        #pragma unroll
        for (int k = 0; k < 5; k++)
            cgt += __popcll(__ballot(ej[k] > ev));
        if (lane == 0 && cgt < TOPK) {
            int p = atomicAdd(&cnt, 1);
            ci[p] = e;
        }
    }
    __syncthreads();
    const int n = cnt;

    // --- gates on kept only ---
    const float tq = tauQ[token], tk = tauK[token];
    float sQ = 0.f, sK = 0.f, mQ = 0.f, mK = 0.f;
    for (int p = t; p < n; p += 256) {
        float s = act[ci[p]];
        float rq = s - tq;
        float gq = (rq > 0.f) ? rq : 1e-8f * __expf(rq);
        float egq = __expf(gq) - 1.f;
        float rk = s - tk;
        float gk = (rk > 0.f) ? rk : 1e-8f * __expf(rk);
        float egk = __expf(gk) - 1.f;
        cwq[p] = egq; cwk[p] = egk;
        sQ += egq; sK += egk;
        mQ = fmaxf(mQ, egq); mK = fmaxf(mK, egk);
    }
    sQ = blk_sum(sQ, sc); mQ = blk_max(mQ, sc);
    sK = blk_sum(sK, sc); mK = blk_max(mK, sc);
    const float scQ = tanhf(mQ) / (sQ + 1e-8f);
    const float scK = tanhf(mK) / (sK + 1e-8f);

    // mask count over all candidates
    float cm = 0.f;
    for (int c = t; c < NCAND; c += 256) cm += msk[c];
    cm = blk_sum(cm, sc);

    // final weights + pos loss (Q gate only, per reference)
    float plq = 0.f;
    for (int p = t; p < n; p += 256) {
        int e = ci[p];
        int id = idx[e];
        float m = msk[e], a = act[e];
        float gq = cwq[p] * scQ;            // normalized Q gate (incl. strength)
        cwq[p] = a * gq * m;
        cwk[p] = a * cwk[p] * scK * m;
        ci[p] = id;
        float d0 = qp0 - npos[id * 2], d1 = qp1 - npos[id * 2 + 1];
        plq += gq * (d0 * d0 + d1 * d1) * m;
    }
    plq = blk_sum(plq, sc);
    if (t == 0) {
        int chunk = s_pos >> 7;
        atomicAdd(&posacc[chunk], plq);
        atomicAdd(&posacc[8 + chunk], cm);
    }
    __syncthreads();

    // --- accumulate Q,K over kept rows (coalesced row reads) ---
    float q0 = 0, q1 = 0, k0 = 0, k1 = 0;
    for (int p = 0; p < n; p++) {
        const float* row = neurons + (size_t)ci[p] * D_;
        float aw = cwq[p], bw = cwk[p];
        float r0 = row[t], r1 = row[t + 256];
        q0 += aw * r0; q1 += aw * r1;
        k0 += bw * r0; k1 += bw * r1;
    }
    const size_t base = (size_t)token * D_;
    Q[base + t] = q0; Q[base + t + 256] = q1;
    K[base + t] = k0; K[base + t + 256] = k1;
}

// ---------- V kernel ----------
__global__ __launch_bounds__(256) void v_kernel(
    const int* __restrict__ order,
    const float* __restrict__ x, const float* __restrict__ v_pos,
    const float* __restrict__ tauV,
    const float* __restrict__ neurons, const float* __restrict__ npos,
    const int* __restrict__ cmap,
    const float* __restrict__ pos_min, const float* __restrict__ pos_range,
    float* __restrict__ V, float* __restrict__ posacc)
{
    __shared__ int   idx[NCAND];
    __shared__ float msk[NCAND], act[NCAND];
    __shared__ int   ci[NCAND];
    __shared__ float cwv[NCAND];
    __shared__ float sc[4];
    __shared__ int   cnt;

    const int pos = (blockIdx.x >> 3) | ((blockIdx.x & 7) << 8);
    const int token = order[pos];
    const int s_pos = token & 1023;
    const int t = threadIdx.x, wid = t >> 6, lane = t & 63;

    const float vp0 = v_pos[token * 2], vp1 = v_pos[token * 2 + 1];
    const float pm0 = pos_min[0], pm1 = pos_min[1];
    const float pr0 = pos_range[0], pr1 = pos_range[1];
    const int cx = min(max((int)((vp0 - pm0) / pr0 * 16.f), 0), 15);
    const int cy = min(max((int)((vp1 - pm1) / pr1 * 16.f), 0), 15);
    for (int c = t; c < NCAND; c += 256) {
        int o = c >> 5, mslot = c & 31;
        int nx = min(max(cx + o / 3 - 1, 0), 15), ny = min(max(cy + o % 3 - 1, 0), 15);
        int cand = cmap[(nx * 16 + ny) * 32 + mslot];
        idx[c] = cand >= 0 ? cand : 0;
        msk[c] = cand >= 0 ? 1.f : 0.f;
    }
    if (t == 0) cnt = 0;
    __syncthreads();

    const float4* x4 = (const float4*)(x + (size_t)token * D_);
    const float4 xa = x4[lane * 2], xb = x4[lane * 2 + 1];
    for (int c = wid * 72; c < wid * 72 + 72; ++c) {
        const float4* r4 = (const float4*)(neurons + (size_t)idx[c] * D_);
        float4 ra = r4[lane * 2], rb = r4[lane * 2 + 1];
        float a = xa.x * ra.x + xa.y * ra.y + xa.z * ra.z + xa.w * ra.w +
                  xb.x * rb.x + xb.y * rb.y + xb.z * rb.z + xb.w * rb.w;
        #pragma unroll
        for (int o = 32; o; o >>= 1) a += __shfl_xor(a, o);
        if (lane == 0) act[c] = (msk[c] != 0.f) ? a : -1e9f;
    }
    __syncthreads();

    float ej[5];
    #pragma unroll
    for (int k = 0; k < 5; k++) {
        int j = lane + 64 * k;
        ej[k] = (j < NCAND) ? act[j] : -1e30f;
    }
    for (int e = wid * 72; e < wid * 72 + 72; e++) {
        float ev = act[e];
        int cgt = 0;
        #pragma unroll
        for (int k = 0; k < 5; k++)
            cgt += __popcll(__ballot(ej[k] > ev));
        if (lane == 0 && cgt < TOPK) {
            int p = atomicAdd(&cnt, 1);
            ci[p] = e;
        }
    }
    __syncthreads();
    const int n = cnt;

    const float tv = tauV[token];
    float sV = 0.f, mV = 0.f;
    for (int p = t; p < n; p += 256) {
        float s = act[ci[p]];
        float rv = s - tv;
        float gv = (rv > 0.f) ? rv : 1e-8f * __expf(rv);
        float egv = __expf(gv) - 1.f;
        cwv[p] = egv;
        sV += egv; mV = fmaxf(mV, egv);
    }
    sV = blk_sum(sV, sc); mV = blk_max(mV, sc);
    const float scV = tanhf(mV) / (sV + 1e-8f);

    float cm = 0.f;
    for (int c = t; c < NCAND; c += 256) cm += msk[c];
    cm = blk_sum(cm, sc);

    float plv = 0.f;
    for (int p = t; p < n; p += 256) {
        int e = ci[p];
        int id = idx[e];
        float m = msk[e], a = act[e];
        float gv = cwv[p] * scV;
        cwv[p] = a * gv * m;
        ci[p] = id;
        float d0 = vp0 - npos[id * 2], d1 = vp1 - npos[id * 2 + 1];
        plv += gv * (d0 * d0 + d1 * d1) * m;
    }
    plv = blk_sum(plv, sc);
    if (t == 0) {
        int chunk = s_pos >> 7;
        atomicAdd(&posacc[16 + chunk], plv);
        atomicAdd(&posacc[24 + chunk], cm);
    }
    __syncthreads();

    float v0 = 0, v1 = 0;
    for (int p = 0; p < n; p++) {
        const float* row = neurons + (size_t)ci[p] * D_;
        float aw = cwv[p];
        v0 += aw * row[t]; v1 += aw * row[t + 256];
    }
    const size_t base = (size_t)token * D_;
    V[base + t] = v0; V[base + t + 256] = v1;
}

// ---------- attention partials (causal-only compact grid) ----------
__global__ __launch_bounds__(256, 2) void attn_partial_kernel(
    const float* __restrict__ Q, const float* __restrict__ K,
    const float* __restrict__ V,
    float* __restrict__ pm, float* __restrict__ pl, float* __restrict__ po,
    int jspan, int jpr)
{
    const int per_bh = 10 * jpr;
    const int bh = blockIdx.x / per_bh;
    int id = blockIdx.x % per_bh;
    int rb = 0;
    while (id >= (rb + 1) * jpr) { id -= (rb + 1) * jpr; rb++; }
    const int sp = id;
    const int b = bh >> 3, h = bh & 7;
    const int j0 = sp * jspan;
    const int t = threadIdx.x;
    const int i = rb * 256 + t;
    const int maxi = rb * 256 + 255;

    __shared__ float Kl[TJ][68];
    __shared__ float Vl[TJ][68];

    float q[64];
    {
        const float4* q4 = (const float4*)(Q + ((size_t)(b * S_ + i)) * D_ + h * DH_);
        #pragma unroll
        for (int k = 0; k < 16; k++) {
            float4 v = q4[k];
            q[4*k] = v.x; q[4*k+1] = v.y; q[4*k+2] = v.z; q[4*k+3] = v.w;
        }
    }
    float o[64];
    #pragma unroll
    for (int d = 0; d < 64; d++) o[d] = 0.f;
    float m = -INFINITY, l = 0.f;

    const int ntiles = min(jspan / TJ, (maxi - j0) / TJ + 1);
    const int ldc = (t & 15) * 4;
    const float* Kbase = K + (size_t)b * S_ * D_ + h * DH_;
    const float* Vbase = V + (size_t)b * S_ * D_ + h * DH_;

    for (int tile = 0; tile < ntiles; tile++) {
        const int jb = j0 + tile * TJ;
        __syncthreads();
        for (int rr = (t >> 4); rr < TJ; rr += 16) {
            const size_t off = (size_t)(jb + rr) * D_ + ldc;
            float4 kv = *(const float4*)(Kbase + off);
            Kl[rr][ldc+0] = kv.x; Kl[rr][ldc+1] = kv.y;
            Kl[rr][ldc+2] = kv.z; Kl[rr][ldc+3] = kv.w;
            float4 vv = *(const float4*)(Vbase + off);
            Vl[rr][ldc+0] = vv.x; Vl[rr][ldc+1] = vv.y;
            Vl[rr][ldc+2] = vv.z; Vl[rr][ldc+3] = vv.w;
        }
        __syncthreads();
        if (jb > i) continue;

        float s[TJ];
        #pragma unroll
        for (int jj = 0; jj < TJ; jj++) {
            float a0 = 0.f, a1 = 0.f, a2 = 0.f, a3 = 0.f;
            #pragma unroll
            for (int d = 0; d < 64; d += 4) {
                a0 += q[d]   * Kl[jj][d];
                a1 += q[d+1] * Kl[jj][d+1];
                a2 += q[d+2] * Kl[jj][d+2];
                a3 += q[d+3] * Kl[jj][d+3];
            }
            float scv = ((a0 + a1) + (a2 + a3)) * 0.125f;
            s[jj] = (jb + jj <= i) ? scv : -INFINITY;
        }
        float tm = s[0];
        #pragma unroll
        for (int jj = 1; jj < TJ; jj++) tm = fmaxf(tm, s[jj]);
        const float nm = fmaxf(m, tm);
        const float alpha = __expf(m - nm);
        float psum = 0.f;
        #pragma unroll
        for (int jj = 0; jj < TJ; jj++) { s[jj] = __expf(s[jj] - nm); psum += s[jj]; }
        l = l * alpha + psum;
        #pragma unroll
        for (int d = 0; d < 64; d++) o[d] *= alpha;
        #pragma unroll
        for (int jj = 0; jj < TJ; jj++) {
            const float pj = s[jj];
            #pragma unroll
            for (int d = 0; d < 64; d++) o[d] += pj * Vl[jj][d];
        }
        m = nm;
    }

    const int r = bh * S_ + i;
    pm[(size_t)sp * NROWS + r] = m;
    pl[(size_t)sp * NROWS + r] = l;
    float* od = po + ((size_t)sp * NROWS + r) * 64;
    #pragma unroll
    for (int k = 0; k < 16; k++) {
        float4 v;
        v.x = o[4*k]; v.y = o[4*k+1]; v.z = o[4*k+2]; v.w = o[4*k+3];
        *(float4*)(od + 4*k) = v;
    }
}

// ---------- merge split partials ----------
__global__ __launch_bounds__(256) void attn_combine_kernel(
    const float* __restrict__ pm, const float* __restrict__ pl,
    const float* __restrict__ po, float* __restrict__ AO, int jshift)
{
    const int gth = blockIdx.x * 256 + threadIdx.x;
    const int r = gth >> 6, d = gth & 63;
    const int i = r & 1023, bh = r >> 10;
    const int b = bh >> 3, h = bh & 7;
    const int ns = (i >> jshift) + 1;
    float mstar = -INFINITY;
    for (int s = 0; s < ns; s++) mstar = fmaxf(mstar, pm[(size_t)s * NROWS + r]);
    float lstar = 0.f, ostar = 0.f;
    for (int s = 0; s < ns; s++) {
        const float w = __expf(pm[(size_t)s * NROWS + r] - mstar);
        lstar += pl[(size_t)s * NROWS + r] * w;
        ostar += po[((size_t)s * NROWS + r) * 64 + d] * w;
    }
    AO[((size_t)(b * S_ + i)) * D_ + h * DH_ + d] = ostar / lstar;
}

// ---------- projection: 4 tokens per block ----------
__global__ __launch_bounds__(256) void proj_kernel(
    const float* __restrict__ A, const float* __restrict__ W,
    float* __restrict__ out)
{
    __shared__ float rows[4][D_];
    const int blk = blockIdx.x;            // 512 blocks
    const int t = threadIdx.x;
    {
        const float4* af = (const float4*)(A + (size_t)blk * 4 * D_);
        float4* rf = (float4*)&rows[0][0];
        rf[t] = af[t]; rf[t + 256] = af[t + 256];
    }
    __syncthreads();
    float acc0[4] = {0,0,0,0}, acc1[4] = {0,0,0,0};
    for (int d = 0; d < D_; d += 4) {
        float r0[4], r1[4], r2[4], r3[4];
        *(float4*)r0 = *(const float4*)&rows[0][d];
        *(float4*)r1 = *(const float4*)&rows[1][d];
        *(float4*)r2 = *(const float4*)&rows[2][d];
        *(float4*)r3 = *(const float4*)&rows[3][d];
        #pragma unroll
        for (int j = 0; j < 4; j++) {
            float w0 = W[(size_t)(d + j) * D_ + t];
            float w1 = W[(size_t)(d + j) * D_ + t + 256];
            acc0[0] += r0[j] * w0; acc1[0] += r0[j] * w1;
            acc0[1] += r1[j] * w0; acc1[1] += r1[j] * w1;
            acc0[2] += r2[j] * w0; acc1[2] += r2[j] * w1;
            acc0[3] += r3[j] * w0; acc1[3] += r3[j] * w1;
        }
    }
    #pragma unroll
    for (int k = 0; k < 4; k++) {
        const size_t base = (size_t)(blk * 4 + k) * D_;
        out[base + t] = acc0[k];
        out[base + t + 256] = acc1[k];
    }
}

// ---------- pos-loss helpers ----------
__global__ void zero_acc_kernel(float* acc) {
    if (threadIdx.x < 32) acc[threadIdx.x] = 0.f;
}
__global__ void ploss_kernel(const float* __restrict__ acc, float* __restrict__ out) {
    float ssum = 0.f;
    for (int c = 0; c < 8; c++) {
        ssum += acc[c]      / (acc[8 + c]  + 1e-8f);
        ssum += acc[16 + c] / (acc[24 + c] + 1e-8f);
    }
    out[0] = ssum * 0.125f;
}

extern "C" void kernel_launch(void* const* d_in, const int* in_sizes, int n_in,
                              void* d_out, int out_size, void* d_ws, size_t ws_size,
                              hipStream_t stream) {
    const float* x          = (const float*)d_in[0];
    const float* qk_pos     = (const float*)d_in[1];
    const float* v_pos      = (const float*)d_in[2];
    const float* tauQ       = (const float*)d_in[3];
    const float* tauK       = (const float*)d_in[4];
    const float* tauV       = (const float*)d_in[5];
    const float* qk_neurons = (const float*)d_in[6];
    const float* v_neurons  = (const float*)d_in[7];
    const float* npos_qk    = (const float*)d_in[8];
    const float* npos_v     = (const float*)d_in[9];
    const int*   cm_qk      = (const int*)d_in[10];
    const int*   cm_v       = (const int*)d_in[11];
    const float* pos_min    = (const float*)d_in[12];
    const float* pos_range  = (const float*)d_in[13];
    const float* expand_O   = (const float*)d_in[14];

    float* ws = (float*)d_ws;
    const size_t TDf = (size_t)NTOK * D_;     // 1,048,576 floats
    float* Q   = ws;
    float* K   = ws + TDf;
    float* V   = ws + 2 * TDf;
    float* AO  = ws + 3 * TDf;
    float* acc = ws + 4 * TDf;                // 64 float slots
    int*   order_qk = (int*)(ws + 4 * TDf + 64);
    int*   order_v  = order_qk + NTOK;
    const size_t head = 4 * TDf + 64 + 2 * NTOK;   // in float units

    const size_t need4 = (head + (size_t)16 * NROWS * 66) * 4;
    const int jpr    = (ws_size >= need4) ? 4 : 2;   // j-splits per 256 rows
    const int jspan  = 256 / jpr;
    const int jshift = (jpr == 4) ? 6 : 7;
    const int NS     = 4 * jpr;

    float* pm = ws + head;
    float* pl = pm + (size_t)NS * NROWS;
    float* po = pl + (size_t)NS * NROWS;

    float* out = (float*)d_out;

    zero_acc_kernel<<<1, 64, 0, stream>>>(acc);
    sort_tokens_kernel<<<1, 1024, 0, stream>>>(qk_pos, v_pos, pos_min, pos_range,
                                               order_qk, order_v);
    qk_kernel<<<NTOK, 256, 0, stream>>>(order_qk, x, qk_pos, tauQ, tauK,
                                        qk_neurons, npos_qk, cm_qk,
                                        pos_min, pos_range, Q, K, acc);
    v_kernel<<<NTOK, 256, 0, stream>>>(order_v, x, v_pos, tauV,
                                       v_neurons, npos_v, cm_v,
                                       pos_min, pos_range, V, acc);
    attn_partial_kernel<<<16 * 10 * jpr, 256, 0, stream>>>(Q, K, V, pm, pl, po,
                                                           jspan, jpr);
    attn_combine_kernel<<<(NROWS * 64) / 256, 256, 0, stream>>>(pm, pl, po, AO, jshift);
    proj_kernel<<<NTOK / 4, 256, 0, stream>>>(AO, expand_O, out);
    ploss_kernel<<<1, 1, 0, stream>>>(acc, out + TDf);
}

// Round 5
// 477.339 us; speedup vs baseline: 1.6564x; 1.2332x over previous
//
#include <hip/hip_runtime.h>
#include <math.h>

#define B_ 2
#define S_ 1024
#define D_ 512
#define N_ 4096
#define H_ 8
#define DH_ 64
#define NCAND 288   // 9 neighbor cells * 32 entries
#define TOPK 32
#define NTOK (B_*S_)   // 2048

#define NROWS 16384       // B*H*S
#define NSLOT_BH 8704     // sum over rows i<1024 of (i/64+1)
#define NSLOTS (16*NSLOT_BH)

// ---------- block-wide reductions (256 threads = 4 waves) ----------
__device__ __forceinline__ float blk_sum(float v, float* sc) {
    #pragma unroll
    for (int o = 32; o; o >>= 1) v += __shfl_xor(v, o);
    __syncthreads();
    if ((threadIdx.x & 63) == 0) sc[threadIdx.x >> 6] = v;
    __syncthreads();
    return sc[0] + sc[1] + sc[2] + sc[3];
}
__device__ __forceinline__ float blk_max(float v, float* sc) {
    #pragma unroll
    for (int o = 32; o; o >>= 1) v = fmaxf(v, __shfl_xor(v, o));
    __syncthreads();
    if ((threadIdx.x & 63) == 0) sc[threadIdx.x >> 6] = v;
    __syncthreads();
    return fmaxf(fmaxf(sc[0], sc[1]), fmaxf(sc[2], sc[3]));
}

// ---------- token sort by spatial cell (1 block, 1024 threads) ----------
__global__ __launch_bounds__(1024) void sort_tokens_kernel(
    const float* __restrict__ qk_pos, const float* __restrict__ v_pos,
    const float* __restrict__ pos_min, const float* __restrict__ pos_range,
    int* __restrict__ order_qk, int* __restrict__ order_v)
{
    __shared__ int hist[256], offs[256], tmp[256];
    const int t = threadIdx.x;
    const float pm0 = pos_min[0], pm1 = pos_min[1];
    const float pr0 = pos_range[0], pr1 = pos_range[1];
    for (int pass = 0; pass < 2; pass++) {
        const float* pos = pass ? v_pos : qk_pos;
        int* order = pass ? order_v : order_qk;
        if (t < 256) hist[t] = 0;
        __syncthreads();
        int cell[2];
        #pragma unroll
        for (int k = 0; k < 2; k++) {
            int tok = t + k * 1024;
            float p0 = pos[tok * 2], p1 = pos[tok * 2 + 1];
            int cx = min(max((int)((p0 - pm0) / pr0 * 16.f), 0), 15);
            int cy = min(max((int)((p1 - pm1) / pr1 * 16.f), 0), 15);
            cell[k] = cx * 16 + cy;
            atomicAdd(&hist[cell[k]], 1);
        }
        __syncthreads();
        if (t < 256) tmp[t] = hist[t];
        __syncthreads();
        for (int d = 1; d < 256; d <<= 1) {
            int v = 0;
            if (t < 256 && t >= d) v = tmp[t - d];
            __syncthreads();
            if (t < 256) tmp[t] += v;
            __syncthreads();
        }
        if (t < 256) offs[t] = tmp[t] - hist[t];
        __syncthreads();
        #pragma unroll
        for (int k = 0; k < 2; k++) {
            int tok = t + k * 1024;
            int p = atomicAdd(&offs[cell[k]], 1);
            order[p] = tok;
        }
        __syncthreads();
    }
}

// ---------- QK kernel (unchanged from R4) ----------
__global__ __launch_bounds__(256) void qk_kernel(
    const int* __restrict__ order,
    const float* __restrict__ x, const float* __restrict__ qk_pos,
    const float* __restrict__ tauQ, const float* __restrict__ tauK,
    const float* __restrict__ neurons, const float* __restrict__ npos,
    const int* __restrict__ cmap,
    const float* __restrict__ pos_min, const float* __restrict__ pos_range,
    float* __restrict__ Q, float* __restrict__ K, float* __restrict__ posacc)
{
    __shared__ int   idx[NCAND];
    __shared__ float msk[NCAND], act[NCAND];
    __shared__ int   ci[NCAND];
    __shared__ float cwq[NCAND], cwk[NCAND];
    __shared__ float sc[4];
    __shared__ int   cnt;

    const int pos = (blockIdx.x >> 3) | ((blockIdx.x & 7) << 8);  // XCD swizzle
    const int token = order[pos];
    const int s_pos = token & 1023;
    const int t = threadIdx.x, wid = t >> 6, lane = t & 63;

    const float qp0 = qk_pos[token * 2], qp1 = qk_pos[token * 2 + 1];
    const float pm0 = pos_min[0], pm1 = pos_min[1];
    const float pr0 = pos_range[0], pr1 = pos_range[1];
    const int cx = min(max((int)((qp0 - pm0) / pr0 * 16.f), 0), 15);
    const int cy = min(max((int)((qp1 - pm1) / pr1 * 16.f), 0), 15);
    for (int c = t; c < NCAND; c += 256) {
        int o = c >> 5, mslot = c & 31;
        int nx = min(max(cx + o / 3 - 1, 0), 15), ny = min(max(cy + o % 3 - 1, 0), 15);
        int cand = cmap[(nx * 16 + ny) * 32 + mslot];
        idx[c] = cand >= 0 ? cand : 0;
        msk[c] = cand >= 0 ? 1.f : 0.f;
    }
    if (t == 0) cnt = 0;
    __syncthreads();

    const float4* x4 = (const float4*)(x + (size_t)token * D_);
    const float4 xa = x4[lane * 2], xb = x4[lane * 2 + 1];
    for (int c = wid * 72; c < wid * 72 + 72; ++c) {
        const float4* r4 = (const float4*)(neurons + (size_t)idx[c] * D_);
        float4 ra = r4[lane * 2], rb = r4[lane * 2 + 1];
        float a = xa.x * ra.x + xa.y * ra.y + xa.z * ra.z + xa.w * ra.w +
                  xb.x * rb.x + xb.y * rb.y + xb.z * rb.z + xb.w * rb.w;
        #pragma unroll
        for (int o = 32; o; o >>= 1) a += __shfl_xor(a, o);
        if (lane == 0) act[c] = (msk[c] != 0.f) ? a : -1e9f;
    }
    __syncthreads();

    float ej[5];
    #pragma unroll
    for (int k = 0; k < 5; k++) {
        int j = lane + 64 * k;
        ej[k] = (j < NCAND) ? act[j] : -1e30f;
    }
    for (int e = wid * 72; e < wid * 72 + 72; e++) {
        float ev = act[e];
        int cgt = 0;
        #pragma unroll
        for (int k = 0; k < 5; k++)
            cgt += __popcll(__ballot(ej[k] > ev));
        if (lane == 0 && cgt < TOPK) {
            int p = atomicAdd(&cnt, 1);
            ci[p] = e;
        }
    }
    __syncthreads();
    const int n = cnt;

    const float tq = tauQ[token], tk = tauK[token];
    float sQ = 0.f, sK = 0.f, mQ = 0.f, mK = 0.f;
    for (int p = t; p < n; p += 256) {
        float s = act[ci[p]];
        float rq = s - tq;
        float gq = (rq > 0.f) ? rq : 1e-8f * __expf(rq);
        float egq = __expf(gq) - 1.f;
        float rk = s - tk;
        float gk = (rk > 0.f) ? rk : 1e-8f * __expf(rk);
        float egk = __expf(gk) - 1.f;
        cwq[p] = egq; cwk[p] = egk;
        sQ += egq; sK += egk;
        mQ = fmaxf(mQ, egq); mK = fmaxf(mK, egk);
    }
    sQ = blk_sum(sQ, sc); mQ = blk_max(mQ, sc);
    sK = blk_sum(sK, sc); mK = blk_max(mK, sc);
    const float scQ = tanhf(mQ) / (sQ + 1e-8f);
    const float scK = tanhf(mK) / (sK + 1e-8f);

    float cm = 0.f;
    for (int c = t; c < NCAND; c += 256) cm += msk[c];
    cm = blk_sum(cm, sc);

    float plq = 0.f;
    for (int p = t; p < n; p += 256) {
        int e = ci[p];
        int id = idx[e];
        float m = msk[e], a = act[e];
        float gq = cwq[p] * scQ;
        cwq[p] = a * gq * m;
        cwk[p] = a * cwk[p] * scK * m;
        ci[p] = id;
        float d0 = qp0 - npos[id * 2], d1 = qp1 - npos[id * 2 + 1];
        plq += gq * (d0 * d0 + d1 * d1) * m;
    }
    plq = blk_sum(plq, sc);
    if (t == 0) {
        int chunk = s_pos >> 7;
        atomicAdd(&posacc[chunk], plq);
        atomicAdd(&posacc[8 + chunk], cm);
    }
    __syncthreads();

    float q0 = 0, q1 = 0, k0 = 0, k1 = 0;
    for (int p = 0; p < n; p++) {
        const float* row = neurons + (size_t)ci[p] * D_;
        float aw = cwq[p], bw = cwk[p];
        float r0 = row[t], r1 = row[t + 256];
        q0 += aw * r0; q1 += aw * r1;
        k0 += bw * r0; k1 += bw * r1;
    }
    const size_t base = (size_t)token * D_;
    Q[base + t] = q0; Q[base + t + 256] = q1;
    K[base + t] = k0; K[base + t + 256] = k1;
}

// ---------- V kernel (unchanged from R4) ----------
__global__ __launch_bounds__(256) void v_kernel(
    const int* __restrict__ order,
    const float* __restrict__ x, const float* __restrict__ v_pos,
    const float* __restrict__ tauV,
    const float* __restrict__ neurons, const float* __restrict__ npos,
    const int* __restrict__ cmap,
    const float* __restrict__ pos_min, const float* __restrict__ pos_range,
    float* __restrict__ V, float* __restrict__ posacc)
{
    __shared__ int   idx[NCAND];
    __shared__ float msk[NCAND], act[NCAND];
    __shared__ int   ci[NCAND];
    __shared__ float cwv[NCAND];
    __shared__ float sc[4];
    __shared__ int   cnt;

    const int pos = (blockIdx.x >> 3) | ((blockIdx.x & 7) << 8);
    const int token = order[pos];
    const int s_pos = token & 1023;
    const int t = threadIdx.x, wid = t >> 6, lane = t & 63;

    const float vp0 = v_pos[token * 2], vp1 = v_pos[token * 2 + 1];
    const float pm0 = pos_min[0], pm1 = pos_min[1];
    const float pr0 = pos_range[0], pr1 = pos_range[1];
    const int cx = min(max((int)((vp0 - pm0) / pr0 * 16.f), 0), 15);
    const int cy = min(max((int)((vp1 - pm1) / pr1 * 16.f), 0), 15);
    for (int c = t; c < NCAND; c += 256) {
        int o = c >> 5, mslot = c & 31;
        int nx = min(max(cx + o / 3 - 1, 0), 15), ny = min(max(cy + o % 3 - 1, 0), 15);
        int cand = cmap[(nx * 16 + ny) * 32 + mslot];
        idx[c] = cand >= 0 ? cand : 0;
        msk[c] = cand >= 0 ? 1.f : 0.f;
    }
    if (t == 0) cnt = 0;
    __syncthreads();

    const float4* x4 = (const float4*)(x + (size_t)token * D_);
    const float4 xa = x4[lane * 2], xb = x4[lane * 2 + 1];
    for (int c = wid * 72; c < wid * 72 + 72; ++c) {
        const float4* r4 = (const float4*)(neurons + (size_t)idx[c] * D_);
        float4 ra = r4[lane * 2], rb = r4[lane * 2 + 1];
        float a = xa.x * ra.x + xa.y * ra.y + xa.z * ra.z + xa.w * ra.w +
                  xb.x * rb.x + xb.y * rb.y + xb.z * rb.z + xb.w * rb.w;
        #pragma unroll
        for (int o = 32; o; o >>= 1) a += __shfl_xor(a, o);
        if (lane == 0) act[c] = (msk[c] != 0.f) ? a : -1e9f;
    }
    __syncthreads();

    float ej[5];
    #pragma unroll
    for (int k = 0; k < 5; k++) {
        int j = lane + 64 * k;
        ej[k] = (j < NCAND) ? act[j] : -1e30f;
    }
    for (int e = wid * 72; e < wid * 72 + 72; e++) {
        float ev = act[e];
        int cgt = 0;
        #pragma unroll
        for (int k = 0; k < 5; k++)
            cgt += __popcll(__ballot(ej[k] > ev));
        if (lane == 0 && cgt < TOPK) {
            int p = atomicAdd(&cnt, 1);
            ci[p] = e;
        }
    }
    __syncthreads();
    const int n = cnt;

    const float tv = tauV[token];
    float sV = 0.f, mV = 0.f;
    for (int p = t; p < n; p += 256) {
        float s = act[ci[p]];
        float rv = s - tv;
        float gv = (rv > 0.f) ? rv : 1e-8f * __expf(rv);
        float egv = __expf(gv) - 1.f;
        cwv[p] = egv;
        sV += egv; mV = fmaxf(mV, egv);
    }
    sV = blk_sum(sV, sc); mV = blk_max(mV, sc);
    const float scV = tanhf(mV) / (sV + 1e-8f);

    float cm = 0.f;
    for (int c = t; c < NCAND; c += 256) cm += msk[c];
    cm = blk_sum(cm, sc);

    float plv = 0.f;
    for (int p = t; p < n; p += 256) {
        int e = ci[p];
        int id = idx[e];
        float m = msk[e], a = act[e];
        float gv = cwv[p] * scV;
        cwv[p] = a * gv * m;
        ci[p] = id;
        float d0 = vp0 - npos[id * 2], d1 = vp1 - npos[id * 2 + 1];
        plv += gv * (d0 * d0 + d1 * d1) * m;
    }
    plv = blk_sum(plv, sc);
    if (t == 0) {
        int chunk = s_pos >> 7;
        atomicAdd(&posacc[16 + chunk], plv);
        atomicAdd(&posacc[24 + chunk], cm);
    }
    __syncthreads();

    float v0 = 0, v1 = 0;
    for (int p = 0; p < n; p++) {
        const float* row = neurons + (size_t)ci[p] * D_;
        float aw = cwv[p];
        v0 += aw * row[t]; v1 += aw * row[t + 256];
    }
    const size_t base = (size_t)token * D_;
    V[base + t] = v0; V[base + t + 256] = v1;
}

// ---------- attention partials v3 ----------
// 1152 blocks x 128 threads. Block = (bh, 128-row block rblk, 64-wide j-split sp).
// Thread: pair p = t>>1 handles rows r0=rblk*128+p, r1=r0+64; dhalf = t&1 owns
// 32 dims. K/V 64x64 tile staged unpadded in LDS (reads are broadcasts).
// Compact po layout: row i stores only its (i/64+1) valid splits.
__global__ __launch_bounds__(128) void attn_partial_kernel(
    const float* __restrict__ Q, const float* __restrict__ K,
    const float* __restrict__ V,
    float* __restrict__ pm, float* __restrict__ pl, float* __restrict__ po)
{
    // XCD-locality mapping: blockIdx%8 selects bh mod 8
    const int xx = blockIdx.x & 7;
    int k = blockIdx.x >> 3;             // 0..143
    const int bh = xx + 8 * (k >= 72);
    k = (k >= 72) ? k - 72 : k;          // 0..71
    int rblk = 0;
    while (k >= 2 * (rblk + 1)) { k -= 2 * (rblk + 1); rblk++; }
    const int sp = k;                    // 0..2*rblk+1
    const int b = bh >> 3, h = bh & 7;
    const int j0 = sp * 64;
    const int rbase = rblk * 128;

    const int t = threadIdx.x;
    const int p = t >> 1, dhalf = t & 1;
    const int r0 = rbase + p, r1 = r0 + 64;

    __shared__ float Kl[64 * 64];
    __shared__ float Vl[64 * 64];

    // cooperative K/V tile load (coalesced: 16 lanes cover one row's 64 floats)
    {
        const float* Kbase = K + (size_t)b * S_ * D_ + h * DH_;
        const float* Vbase = V + (size_t)b * S_ * D_ + h * DH_;
        const int lrow = t >> 4, lcol = (t & 15) * 4;
        #pragma unroll
        for (int kk = 0; kk < 8; kk++) {
            const int row = lrow + kk * 8;
            const size_t goff = (size_t)(j0 + row) * D_ + lcol;
            *(float4*)(&Kl[row * 64 + lcol]) = *(const float4*)(Kbase + goff);
            *(float4*)(&Vl[row * 64 + lcol]) = *(const float4*)(Vbase + goff);
        }
    }

    // Q halves for both rows
    float q0[32], q1[32];
    {
        const float* Qb = Q + (size_t)b * S_ * D_ + h * DH_ + dhalf * 32;
        const float4* qa = (const float4*)(Qb + (size_t)r0 * D_);
        const float4* qb = (const float4*)(Qb + (size_t)r1 * D_);
        #pragma unroll
        for (int kk = 0; kk < 8; kk++) {
            float4 v = qa[kk];
            q0[4*kk] = v.x; q0[4*kk+1] = v.y; q0[4*kk+2] = v.z; q0[4*kk+3] = v.w;
            float4 u = qb[kk];
            q1[4*kk] = u.x; q1[4*kk+1] = u.y; q1[4*kk+2] = u.z; q1[4*kk+3] = u.w;
        }
    }
    float o0[32], o1[32];
    #pragma unroll
    for (int d = 0; d < 32; d++) { o0[d] = 0.f; o1[d] = 0.f; }
    float m0 = -INFINITY, m1 = -INFINITY, l0 = 0.f, l1 = 0.f;

    __syncthreads();

    for (int bb = 0; bb < 8; bb++) {
        const int jb = bb * 8;
        float s0[8], s1[8];
        #pragma unroll
        for (int jj = 0; jj < 8; jj++) {
            const float* kr = &Kl[(jb + jj) * 64 + dhalf * 32];
            float pa0 = 0.f, pb0 = 0.f, pa1 = 0.f, pb1 = 0.f;
            #pragma unroll
            for (int d = 0; d < 32; d += 8) {
                float4 ka = *(const float4*)(kr + d);
                float4 kb = *(const float4*)(kr + d + 4);
                pa0 += q0[d]*ka.x + q0[d+1]*ka.y + q0[d+2]*ka.z + q0[d+3]*ka.w;
                pb0 += q0[d+4]*kb.x + q0[d+5]*kb.y + q0[d+6]*kb.z + q0[d+7]*kb.w;
                pa1 += q1[d]*ka.x + q1[d+1]*ka.y + q1[d+2]*ka.z + q1[d+3]*ka.w;
                pb1 += q1[d+4]*kb.x + q1[d+5]*kb.y + q1[d+6]*kb.z + q1[d+7]*kb.w;
            }
            float f0 = pa0 + pb0, f1 = pa1 + pb1;
            f0 += __shfl_xor(f0, 1);    // combine d-halves (lane pair)
            f1 += __shfl_xor(f1, 1);
            const int jg = j0 + jb + jj;
            s0[jj] = (jg <= r0) ? f0 * 0.125f : -INFINITY;
            s1[jj] = (jg <= r1) ? f1 * 0.125f : -INFINITY;
        }
        float t0 = s0[0], t1 = s1[0];
        #pragma unroll
        for (int jj = 1; jj < 8; jj++) { t0 = fmaxf(t0, s0[jj]); t1 = fmaxf(t1, s1[jj]); }
        const float nm0 = fmaxf(m0, t0), nm1 = fmaxf(m1, t1);
        const float base0 = (nm0 == -INFINITY) ? 0.f : nm0;  // nan guard
        const float base1 = (nm1 == -INFINITY) ? 0.f : nm1;
        const float al0 = __expf(m0 - base0);
        const float al1 = __expf(m1 - base1);
        float ps0 = 0.f, ps1 = 0.f;
        #pragma unroll
        for (int jj = 0; jj < 8; jj++) {
            s0[jj] = __expf(s0[jj] - base0); ps0 += s0[jj];
            s1[jj] = __expf(s1[jj] - base1); ps1 += s1[jj];
        }
        l0 = l0 * al0 + ps0; l1 = l1 * al1 + ps1;
        #pragma unroll
        for (int d = 0; d < 32; d++) { o0[d] *= al0; o1[d] *= al1; }
        #pragma unroll
        for (int jj = 0; jj < 8; jj++) {
            const float* vr = &Vl[(jb + jj) * 64 + dhalf * 32];
            const float w0 = s0[jj], w1 = s1[jj];
            #pragma unroll
            for (int d = 0; d < 32; d += 4) {
                float4 vv = *(const float4*)(vr + d);
                o0[d]   += w0 * vv.x; o0[d+1] += w0 * vv.y;
                o0[d+2] += w0 * vv.z; o0[d+3] += w0 * vv.w;
                o1[d]   += w1 * vv.x; o1[d+1] += w1 * vv.y;
                o1[d+2] += w1 * vv.z; o1[d+3] += w1 * vv.w;
            }
        }
        m0 = nm0; m1 = nm1;
    }

    // compact store: slot(bh,i,sp) = bh*8704 + 32*g*(g+1) + (i&63)*(g+1) + sp
    if (j0 <= r0) {                         // top split skips lower rows
        const int g = r0 >> 6;
        const size_t slot = (size_t)bh * NSLOT_BH + 32 * g * (g + 1)
                          + (size_t)(r0 & 63) * (g + 1) + sp;
        if (dhalf == 0) { pm[slot] = m0; pl[slot] = l0; }
        float* od = po + slot * 64 + dhalf * 32;
        #pragma unroll
        for (int kk = 0; kk < 8; kk++) {
            float4 v; v.x = o0[4*kk]; v.y = o0[4*kk+1]; v.z = o0[4*kk+2]; v.w = o0[4*kk+3];
            *(float4*)(od + 4*kk) = v;
        }
    }
    {                                       // r1 always >= j0
        const int g = r1 >> 6;
        const size_t slot = (size_t)bh * NSLOT_BH + 32 * g * (g + 1)
                          + (size_t)(r1 & 63) * (g + 1) + sp;
        if (dhalf == 0) { pm[slot] = m1; pl[slot] = l1; }
        float* od = po + slot * 64 + dhalf * 32;
        #pragma unroll
        for (int kk = 0; kk < 8; kk++) {
            float4 v; v.x = o1[4*kk]; v.y = o1[4*kk+1]; v.z = o1[4*kk+2]; v.w = o1[4*kk+3];
            *(float4*)(od + 4*kk) = v;
        }
    }
}

// ---------- merge split partials (compact layout) ----------
__global__ __launch_bounds__(256) void attn_combine_kernel(
    const float* __restrict__ pm, const float* __restrict__ pl,
    const float* __restrict__ po, float* __restrict__ AO)
{
    const int gth = blockIdx.x * 256 + threadIdx.x;
    const int r = gth >> 6, d = gth & 63;
    const int i = r & 1023, bh = r >> 10;
    const int b = bh >> 3, h = bh & 7;
    const int g = i >> 6;
    const int ns = g + 1;
    const size_t slot0 = (size_t)bh * NSLOT_BH + 32 * g * (g + 1)
                       + (size_t)(i & 63) * (g + 1);
    float mstar = -INFINITY;
    for (int s = 0; s < ns; s++) mstar = fmaxf(mstar, pm[slot0 + s]);
    float lstar = 0.f, ostar = 0.f;
    for (int s = 0; s < ns; s++) {
        const float w = __expf(pm[slot0 + s] - mstar);
        lstar += pl[slot0 + s] * w;
        ostar += po[(slot0 + s) * 64 + d] * w;
    }
    AO[((size_t)(b * S_ + i)) * D_ + h * DH_ + d] = ostar / lstar;
}

// ---------- projection: 4 tokens per block ----------
__global__ __launch_bounds__(256) void proj_kernel(
    const float* __restrict__ A, const float* __restrict__ W,
    float* __restrict__ out)
{
    __shared__ float rows[4][D_];
    const int blk = blockIdx.x;            // 512 blocks
    const int t = threadIdx.x;
    {
        const float4* af = (const float4*)(A + (size_t)blk * 4 * D_);
        float4* rf = (float4*)&rows[0][0];
        rf[t] = af[t]; rf[t + 256] = af[t + 256];
    }
    __syncthreads();
    float acc0[4] = {0,0,0,0}, acc1[4] = {0,0,0,0};
    for (int d = 0; d < D_; d += 4) {
        float r0[4], r1[4], r2[4], r3[4];
        *(float4*)r0 = *(const float4*)&rows[0][d];
        *(float4*)r1 = *(const float4*)&rows[1][d];
        *(float4*)r2 = *(const float4*)&rows[2][d];
        *(float4*)r3 = *(const float4*)&rows[3][d];
        #pragma unroll
        for (int j = 0; j < 4; j++) {
            float w0 = W[(size_t)(d + j) * D_ + t];
            float w1 = W[(size_t)(d + j) * D_ + t + 256];
            acc0[0] += r0[j] * w0; acc1[0] += r0[j] * w1;
            acc0[1] += r1[j] * w0; acc1[1] += r1[j] * w1;
            acc0[2] += r2[j] * w0; acc1[2] += r2[j] * w1;
            acc0[3] += r3[j] * w0; acc1[3] += r3[j] * w1;
        }
    }
    #pragma unroll
    for (int k = 0; k < 4; k++) {
        const size_t base = (size_t)(blk * 4 + k) * D_;
        out[base + t] = acc0[k];
        out[base + t + 256] = acc1[k];
    }
}

// ---------- pos-loss helpers ----------
__global__ void zero_acc_kernel(float* acc) {
    if (threadIdx.x < 32) acc[threadIdx.x] = 0.f;
}
__global__ void ploss_kernel(const float* __restrict__ acc, float* __restrict__ out) {
    float ssum = 0.f;
    for (int c = 0; c < 8; c++) {
        ssum += acc[c]      / (acc[8 + c]  + 1e-8f);
        ssum += acc[16 + c] / (acc[24 + c] + 1e-8f);
    }
    out[0] = ssum * 0.125f;
}

extern "C" void kernel_launch(void* const* d_in, const int* in_sizes, int n_in,
                              void* d_out, int out_size, void* d_ws, size_t ws_size,
                              hipStream_t stream) {
    const float* x          = (const float*)d_in[0];
    const float* qk_pos     = (const float*)d_in[1];
    const float* v_pos      = (const float*)d_in[2];
    const float* tauQ       = (const float*)d_in[3];
    const float* tauK       = (const float*)d_in[4];
    const float* tauV       = (const float*)d_in[5];
    const float* qk_neurons = (const float*)d_in[6];
    const float* v_neurons  = (const float*)d_in[7];
    const float* npos_qk    = (const float*)d_in[8];
    const float* npos_v     = (const float*)d_in[9];
    const int*   cm_qk      = (const int*)d_in[10];
    const int*   cm_v       = (const int*)d_in[11];
    const float* pos_min    = (const float*)d_in[12];
    const float* pos_range  = (const float*)d_in[13];
    const float* expand_O   = (const float*)d_in[14];

    float* ws = (float*)d_ws;
    const size_t TDf = (size_t)NTOK * D_;     // 1,048,576 floats
    float* Q   = ws;
    float* K   = ws + TDf;
    float* V   = ws + 2 * TDf;
    float* AO  = ws + 3 * TDf;
    float* acc = ws + 4 * TDf;                // 64 float slots
    int*   order_qk = (int*)(ws + 4 * TDf + 64);
    int*   order_v  = order_qk + NTOK;
    const size_t head = 4 * TDf + 64 + 2 * NTOK;   // float units

    float* pm = ws + head;                    // NSLOTS
    float* pl = pm + (size_t)NSLOTS;
    float* po = pl + (size_t)NSLOTS;          // NSLOTS*64 (~35.7 MB)

    float* out = (float*)d_out;

    zero_acc_kernel<<<1, 64, 0, stream>>>(acc);
    sort_tokens_kernel<<<1, 1024, 0, stream>>>(qk_pos, v_pos, pos_min, pos_range,
                                               order_qk, order_v);
    qk_kernel<<<NTOK, 256, 0, stream>>>(order_qk, x, qk_pos, tauQ, tauK,
                                        qk_neurons, npos_qk, cm_qk,
                                        pos_min, pos_range, Q, K, acc);
    v_kernel<<<NTOK, 256, 0, stream>>>(order_v, x, v_pos, tauV,
                                       v_neurons, npos_v, cm_v,
                                       pos_min, pos_range, V, acc);
    attn_partial_kernel<<<1152, 128, 0, stream>>>(Q, K, V, pm, pl, po);
    attn_combine_kernel<<<(NROWS * 64) / 256, 256, 0, stream>>>(pm, pl, po, AO);
    proj_kernel<<<NTOK / 4, 256, 0, stream>>>(AO, expand_O, out);
    ploss_kernel<<<1, 1, 0, stream>>>(acc, out + TDf);
}